// Round 1
// 1046.671 us; speedup vs baseline: 1.3119x; 1.3119x over previous
//
#include <hip/hip_runtime.h>
#include <math.h>

typedef __attribute__((ext_vector_type(8))) short short8;
typedef __attribute__((ext_vector_type(4))) float floatx4;

#define TOKENS 50176   // 16 * 64 windows * 49
#define HTOK   25088   // TOKENS/2 (fc1/fc2 row chunk)

__device__ __forceinline__ unsigned short f2bf(float f) {
  union { float f; unsigned int i; } x; x.f = f;
  unsigned int r = x.i + 0x7fffu + ((x.i >> 16) & 1u);
  return (unsigned short)(r >> 16);
}
__device__ __forceinline__ float bf2f(unsigned short u) {
  union { unsigned int i; float f; } x; x.i = ((unsigned int)u) << 16; return x.f;
}

// async global->LDS, 16B per lane; LDS dest = wave-uniform base + lane*16
__device__ __forceinline__ void gload16(const void* g, void* l) {
  __builtin_amdgcn_global_load_lds(
      (__attribute__((address_space(1))) void*)g,
      (__attribute__((address_space(3))) void*)l, 16, 0, 0);
}

// -------------------------------------------------------------------------
// fp32 -> bf16 weight conversion (one-time). n8 = elements/8.
// -------------------------------------------------------------------------
__global__ __launch_bounds__(256) void wcvt(
    const float* __restrict__ src, unsigned short* __restrict__ dst, int n8) {
  int i = blockIdx.x * 256 + threadIdx.x;
  if (i >= n8) return;
  const float* p = src + (size_t)i * 8;
  floatx4 a = *(const floatx4*)p;
  floatx4 b = *(const floatx4*)(p + 4);
  short8 o;
#pragma unroll
  for (int k = 0; k < 4; ++k) { o[k] = (short)f2bf(a[k]); o[k + 4] = (short)f2bf(b[k]); }
  *(short8*)(dst + (size_t)i * 8) = o;
}

// -------------------------------------------------------------------------
// LN1 + roll(-3,-3) + window-partition gather, fp32 -> bf16.
// One wave per destination (windowed) token.
// -------------------------------------------------------------------------
__global__ __launch_bounds__(256) void prep_ln1(
    const float* __restrict__ x1, const float* __restrict__ g,
    const float* __restrict__ b, unsigned short* __restrict__ a1w) {
  int gw = (blockIdx.x * 256 + threadIdx.x) >> 6;
  int lane = threadIdx.x & 63;
  if (gw >= TOKENS) return;
  int n = gw % 49, w = gw / 49;
  int i = n / 7, j = n % 7;
  int ww = w & 7, wh = (w >> 3) & 7, bb = w >> 6;
  int hs = (wh * 7 + i + 3) % 56;
  int wsS = (ww * 7 + j + 3) % 56;
  const float* rp = x1 + ((size_t)bb * 3136 + (size_t)hs * 56 + wsS) * 512 + lane * 8;
  floatx4 a0 = *(const floatx4*)rp;
  floatx4 a1 = *(const floatx4*)(rp + 4);
  float s = 0.f, ss = 0.f;
#pragma unroll
  for (int k = 0; k < 4; ++k) { s += a0[k]; ss += a0[k] * a0[k]; }
#pragma unroll
  for (int k = 0; k < 4; ++k) { s += a1[k]; ss += a1[k] * a1[k]; }
  for (int m = 32; m >= 1; m >>= 1) {
    s  += __shfl_xor(s, m, 64);
    ss += __shfl_xor(ss, m, 64);
  }
  float mu = s * (1.f / 512.f);
  float var = ss * (1.f / 512.f) - mu * mu;
  float rstd = rsqrtf(var + 1e-5f);
  floatx4 g0 = *(const floatx4*)(g + lane * 8);
  floatx4 g1 = *(const floatx4*)(g + lane * 8 + 4);
  floatx4 b0 = *(const floatx4*)(b + lane * 8);
  floatx4 b1 = *(const floatx4*)(b + lane * 8 + 4);
  short8 o8;
#pragma unroll
  for (int k = 0; k < 4; ++k) {
    o8[k]     = (short)f2bf((a0[k] - mu) * rstd * g0[k] + b0[k]);
    o8[k + 4] = (short)f2bf((a1[k] - mu) * rstd * g1[k] + b1[k]);
  }
  *(short8*)(a1w + (size_t)gw * 512 + lane * 8) = o8;
}

// -------------------------------------------------------------------------
// LN2 full apply: fp32 row -> normalized bf16 row. One wave per token.
// -------------------------------------------------------------------------
__global__ __launch_bounds__(256) void ln2_apply(
    const float* __restrict__ xin, const float* __restrict__ g,
    const float* __restrict__ b, unsigned short* __restrict__ outb) {
  int gw = (blockIdx.x * 256 + threadIdx.x) >> 6;
  int lane = threadIdx.x & 63;
  if (gw >= TOKENS) return;
  const float* rp = xin + (size_t)gw * 512 + lane * 8;
  floatx4 a0 = *(const floatx4*)rp;
  floatx4 a1 = *(const floatx4*)(rp + 4);
  float s = 0.f, ss = 0.f;
#pragma unroll
  for (int k = 0; k < 4; ++k) { s += a0[k]; ss += a0[k] * a0[k]; }
#pragma unroll
  for (int k = 0; k < 4; ++k) { s += a1[k]; ss += a1[k] * a1[k]; }
  for (int m = 32; m >= 1; m >>= 1) {
    s  += __shfl_xor(s, m, 64);
    ss += __shfl_xor(ss, m, 64);
  }
  float mu = s * (1.f / 512.f);
  float var = ss * (1.f / 512.f) - mu * mu;
  float rstd = rsqrtf(var + 1e-5f);
  floatx4 g0 = *(const floatx4*)(g + lane * 8);
  floatx4 g1 = *(const floatx4*)(g + lane * 8 + 4);
  floatx4 b0 = *(const floatx4*)(b + lane * 8);
  floatx4 b1 = *(const floatx4*)(b + lane * 8 + 4);
  short8 o8;
#pragma unroll
  for (int k = 0; k < 4; ++k) {
    o8[k]     = (short)f2bf((a0[k] - mu) * rstd * g0[k] + b0[k]);
    o8[k + 4] = (short)f2bf((a1[k] - mu) * rstd * g1[k] + b1[k]);
  }
  *(short8*)(outb + (size_t)gw * 512 + lane * 8) = o8;
}

// -------------------------------------------------------------------------
// m97-structure GEMM: out[m,n] = sum_k A[m,k]*Bw[n,k] + bias[n]
// A, Bw both bf16. 128x128 tile, BK=64, 4 waves, global_load_lds staging
// (linear LDS, no pad), 16x16x32 bf16 MFMA. grid = (M/128, N/128).
// EPI 0: +bias -> bf16 out[m*N+n]
// EPI 1: +bias, reverse/roll row scatter, +res -> fp32 out (orig layout)
// EPI 2: +bias, exact GELU -> bf16 out[m*N+n]
// EPI 3: +bias, +res[m*512+n] -> fp32 out[m*512+n] (in place)
// -------------------------------------------------------------------------
template <int EPI>
__global__ __launch_bounds__(256, 2) void gemm_glds(
    const unsigned short* __restrict__ A,
    const unsigned short* __restrict__ Bw,
    const float* __restrict__ bias,
    void* __restrict__ outp,
    const float* __restrict__ res,
    int N, int K, int lda) {
  __shared__ unsigned short lA[128 * 64];
  __shared__ unsigned short lB[128 * 64];
  int tid = threadIdx.x;
  int wave = tid >> 6, lane = tid & 63;

  // staging: chunk cc = wave*4+i covers rows cc*8 + lane/8, cols (lane&7)*8..+8
  int srow = wave * 32 + (lane >> 3);
  int scol = (lane & 7) * 8;
  const unsigned short* gA[4];
  const unsigned short* gB[4];
#pragma unroll
  for (int i = 0; i < 4; ++i) {
    gA[i] = A + (size_t)(blockIdx.x * 128 + srow + i * 8) * lda + scol;
    gB[i] = Bw + (size_t)(blockIdx.y * 128 + srow + i * 8) * K + scol;
  }
  unsigned short* lAp = &lA[wave * 2048];  // wave-uniform chunk bases
  unsigned short* lBp = &lB[wave * 2048];

  int wm = (wave >> 1) * 64, wn = (wave & 1) * 64;
  int l15 = lane & 15, kq = (lane >> 4) * 8;
  int KT = K >> 6;
  floatx4 acc[4][4] = {};

  for (int kt = 0; kt < KT; ++kt) {
    int ko = kt * 64;
#pragma unroll
    for (int i = 0; i < 4; ++i) {
      gload16(gA[i] + ko, lAp + i * 512);
      gload16(gB[i] + ko, lBp + i * 512);
    }
    __syncthreads();  // compiler drains vmcnt(0) before s_barrier
#pragma unroll
    for (int ks = 0; ks < 2; ++ks) {
      short8 af[4], bf8[4];
#pragma unroll
      for (int tm = 0; tm < 4; ++tm)
        af[tm] = *(const short8*)&lA[(wm + tm * 16 + l15) * 64 + ks * 32 + kq];
#pragma unroll
      for (int tn = 0; tn < 4; ++tn)
        bf8[tn] = *(const short8*)&lB[(wn + tn * 16 + l15) * 64 + ks * 32 + kq];
#pragma unroll
      for (int tm = 0; tm < 4; ++tm)
#pragma unroll
        for (int tn = 0; tn < 4; ++tn)
          acc[tm][tn] = __builtin_amdgcn_mfma_f32_16x16x32_bf16(
              af[tm], bf8[tn], acc[tm][tn], 0, 0, 0);
    }
    __syncthreads();
  }

  // ---- epilogue (D row = (lane>>4)*4+reg, D col = lane&15) ----
  int colb = blockIdx.y * 128 + wn + l15;
  int rowb = blockIdx.x * 128 + wm + ((lane >> 4) << 2);
#pragma unroll
  for (int tm = 0; tm < 4; ++tm) {
#pragma unroll
    for (int rg = 0; rg < 4; ++rg) {
      int m = rowb + tm * 16 + rg;
      size_t outrow;
      const float* resrow = nullptr;
      if (EPI == 1) {
        int nn = m % 49, wI = m / 49;
        int i = nn / 7, j = nn % 7;
        int wwI = wI & 7, whI = (wI >> 3) & 7, bb = wI >> 6;
        int hs = (whI * 7 + i + 3) % 56;
        int wsS = (wwI * 7 + j + 3) % 56;
        size_t orig = (size_t)bb * 3136 + (size_t)hs * 56 + wsS;
        outrow = orig * 512;
        resrow = res + orig * 512;
      } else {
        outrow = (size_t)m * N;
        if (EPI == 3) resrow = res + (size_t)m * 512;
      }
#pragma unroll
      for (int tn = 0; tn < 4; ++tn) {
        int n = colb + tn * 16;
        float v = acc[tm][tn][rg] + bias[n];
        if (EPI == 2) v = 0.5f * v * (1.f + erff(v * 0.70710678118654752f));
        if (EPI == 0 || EPI == 2) {
          ((unsigned short*)outp)[outrow + n] = f2bf(v);
        } else {
          ((float*)outp)[outrow + n] = v + resrow[n];
        }
      }
    }
  }
}

// -------------------------------------------------------------------------
// Windowed attention, x1 branch only (x2 branch dead in reference:
// xw[:,:,:C] selects heads 0..15 = attn1@v1; softmax is per-head-row).
// One block per window; 4 waves x 4 heads each. O written IN PLACE into the
// Q columns of the qkv buffer (each head's Q is dead once consumed).
// -------------------------------------------------------------------------
__global__ __launch_bounds__(256) void attn_kernel(
    unsigned short* qkv,                      // (1024*49, 1536) bf16, in/out
    const float* __restrict__ rel_tab) {      // (169,16) fp32
  __shared__ float ldsK[4][49 * 32];
  __shared__ float ldsV[4][49 * 32];
  int wg = blockIdx.x;
  int wave = threadIdx.x >> 6, lane = threadIdx.x & 63;
  int wh = (wg >> 3) & 7, ww = wg & 7;
  int r = lane;
  int ir = r / 7, jr = r % 7;
  int rh = (wh < 7) ? 0 : ((ir < 4) ? 1 : 2);
  int rw = (ww < 7) ? 0 : ((jr < 4) ? 1 : 2);
  int labr = rh * 3 + rw;
  const size_t base = (size_t)wg * 49 * 1536;

  for (int hh = 0; hh < 4; ++hh) {
    int head = wave * 4 + hh;
    __syncthreads();
    for (int idx = lane; idx < 49 * 32; idx += 64) {
      int rr = idx >> 5, d = idx & 31;
      size_t ro = base + (size_t)rr * 1536 + head * 32 + d;
      ldsK[wave][idx] = bf2f(qkv[ro + 512]);
      ldsV[wave][idx] = bf2f(qkv[ro + 1024]);
    }
    __syncthreads();
    if (r < 49) {
      float qf[32];
#pragma unroll
      for (int d8 = 0; d8 < 4; ++d8) {
        short8 raw = *(const short8*)(qkv + base + (size_t)r * 1536 + head * 32 + d8 * 8);
#pragma unroll
        for (int k = 0; k < 8; ++k) qf[d8 * 8 + k] = bf2f((unsigned short)raw[k]);
      }
      float sarr[49];
      float mx = -1e30f;
#pragma unroll
      for (int c = 0; c < 49; ++c) {
        float dot = 0.f;
#pragma unroll
        for (int d = 0; d < 32; ++d) dot += qf[d] * ldsK[wave][c * 32 + d];
        int ic = c / 7, jc = c % 7;
        int ch = (wh < 7) ? 0 : ((ic < 4) ? 1 : 2);
        int cw = (ww < 7) ? 0 : ((jc < 4) ? 1 : 2);
        float mask = ((ch * 3 + cw) != labr) ? -100.f : 0.f;
        int ridx = (ir - ic + 6) * 13 + (jr - jc + 6);
        float sv = dot * 0.17677669529663687f + rel_tab[ridx * 16 + head] + mask;
        sarr[c] = sv;
        mx = fmaxf(mx, sv);
      }
      float sum = 0.f;
#pragma unroll
      for (int c = 0; c < 49; ++c) { float e = __expf(sarr[c] - mx); sarr[c] = e; sum += e; }
      float inv = 1.f / sum;
      float o[32];
#pragma unroll
      for (int d = 0; d < 32; ++d) o[d] = 0.f;
#pragma unroll
      for (int c = 0; c < 49; ++c) {
        float p = sarr[c];
#pragma unroll
        for (int d = 0; d < 32; ++d) o[d] += p * ldsV[wave][c * 32 + d];
      }
      unsigned short* dst = qkv + base + (size_t)r * 1536 + head * 32;  // in place
#pragma unroll
      for (int d8 = 0; d8 < 4; ++d8) {
        short8 pk;
#pragma unroll
        for (int k = 0; k < 8; ++k) pk[k] = (short)f2bf(o[d8 * 8 + k] * inv);
        *(short8*)(dst + d8 * 8) = pk;
      }
    }
  }
}

// -------------------------------------------------------------------------
extern "C" void kernel_launch(void* const* d_in, const int* in_sizes, int n_in,
                              void* d_out, int out_size, void* d_ws, size_t ws_size,
                              hipStream_t stream) {
  const float* x1     = (const float*)d_in[0];
  // d_in[1] = x2 : dead code in reference (xw[:,:,:C] uses only the x1 branch)
  const float* n1g    = (const float*)d_in[2];
  const float* n1b    = (const float*)d_in[3];
  const float* qkv_w  = (const float*)d_in[4];
  const float* qkv_b  = (const float*)d_in[5];
  const float* rel_t  = (const float*)d_in[6];
  const float* proj_w = (const float*)d_in[7];
  const float* proj_b = (const float*)d_in[8];
  const float* n2g    = (const float*)d_in[9];
  const float* n2b    = (const float*)d_in[10];
  const float* fc1_w  = (const float*)d_in[11];
  const float* fc1_b  = (const float*)d_in[12];
  const float* fc2_w  = (const float*)d_in[13];
  const float* fc2_b  = (const float*)d_in[14];
  float* outp = (float*)d_out;   // fp32; also holds x (residual-1 result)

  // ws layout, phase-aware (ws = 205,922,304 B):
  //  phase A (LN1..proj):  a1w  [0 .. 51,380,224)          bf16 windowed LN1
  //                        bufQ [51,380,224 .. 205,520,896) bf16 QKV / O
  //  after QKV (a1w dead): pwbf  [0 .. 524,288)            proj_w bf16
  //                        f1wbf [524,288 .. 2,621,440)    fc1_w bf16
  //                        f2wbf [2,621,440 .. 4,718,592)  fc2_w bf16
  //  after proj (bufQ dead): xln2 [4,718,592 .. 56,098,816)  LN2(x) bf16
  //                          hbuf [56,098,816 .. 158,859,264) fc1 out, 1/2 rows
  //  qkv_wbf parks in d_out (dead until proj writes it).
  char* ws = (char*)d_ws;
  unsigned short* a1w    = (unsigned short*)ws;
  unsigned short* bufQ   = (unsigned short*)(ws + 51380224);
  unsigned short* pwbf   = (unsigned short*)ws;
  unsigned short* f1wbf  = (unsigned short*)(ws + 524288);
  unsigned short* f2wbf  = (unsigned short*)(ws + 2621440);
  unsigned short* xln2   = (unsigned short*)(ws + 4718592);
  unsigned short* hbuf   = (unsigned short*)(ws + 56098816);
  unsigned short* qkvwbf = (unsigned short*)d_out;

  // 0. qkv weights -> bf16 (in d_out scratch); LN1 + roll + partition
  wcvt<<<384, 256, 0, stream>>>(qkv_w, qkvwbf, 98304);
  prep_ln1<<<TOKENS / 4, 256, 0, stream>>>(x1, n1g, n1b, a1w);
  // 2. QKV: 50176x1536x512, grid (392,12)
  gemm_glds<0><<<dim3(392, 12), 256, 0, stream>>>(
      a1w, qkvwbf, qkv_b, bufQ, nullptr, 1536, 512, 512);
  // remaining weights -> bf16 (a1w region is dead now)
  wcvt<<<128, 256, 0, stream>>>(proj_w, pwbf, 32768);
  wcvt<<<512, 256, 0, stream>>>(fc1_w, f1wbf, 131072);
  wcvt<<<512, 256, 0, stream>>>(fc2_w, f2wbf, 131072);
  // 3. attention (O in place into Q columns)
  attn_kernel<<<1024, 256, 0, stream>>>(bufQ, rel_t);
  // 4. proj: A = O (stride 1536), scatter + x1 residual -> d_out fp32
  gemm_glds<1><<<dim3(392, 4), 256, 0, stream>>>(
      bufQ, pwbf, proj_b, outp, x1, 512, 512, 1536);
  // 5. LN2 apply -> bf16 xln2
  ln2_apply<<<TOKENS / 4, 256, 0, stream>>>(outp, n2g, n2b, xln2);
  // 6/7. fc1 (GELU) + fc2 (+x residual, in place), 2 row-chunks of 25088
  for (int ch = 0; ch < 2; ++ch) {
    size_t ro = (size_t)ch * HTOK * 512;
    gemm_glds<2><<<dim3(196, 16), 256, 0, stream>>>(
        xln2 + ro, f1wbf, fc1_b, hbuf, nullptr, 2048, 512, 512);
    gemm_glds<3><<<dim3(196, 4), 256, 0, stream>>>(
        hbuf, f2wbf, fc2_b, outp + ro, outp + ro, 512, 2048, 2048);
  }
}

// Round 4
// 990.249 us; speedup vs baseline: 1.3867x; 1.0570x over previous
//
#include <hip/hip_runtime.h>
#include <math.h>

typedef __attribute__((ext_vector_type(8))) short short8;
typedef __attribute__((ext_vector_type(4))) float floatx4;

#define TOKENS 50176   // 16 * 64 windows * 49
#define HTOK   25088   // TOKENS/2 (fc1/fc2 row chunk)

__device__ __forceinline__ unsigned short f2bf(float f) {
  union { float f; unsigned int i; } x; x.f = f;
  unsigned int r = x.i + 0x7fffu + ((x.i >> 16) & 1u);
  return (unsigned short)(r >> 16);
}
__device__ __forceinline__ float bf2f(unsigned short u) {
  union { unsigned int i; float f; } x; x.i = ((unsigned int)u) << 16; return x.f;
}

// async global->LDS, 16B per lane; LDS dest = wave-uniform base + lane*16
__device__ __forceinline__ void gload16(const void* g, void* l) {
  __builtin_amdgcn_global_load_lds(
      (__attribute__((address_space(1))) void*)g,
      (__attribute__((address_space(3))) void*)l, 16, 0, 0);
}

__device__ __forceinline__ unsigned cvtpk(float lo, float hi) {
  unsigned r;
  asm("v_cvt_pk_bf16_f32 %0, %1, %2" : "=v"(r) : "v"(lo), "v"(hi));
  return r;
}

// -------------------------------------------------------------------------
// fp32 -> bf16 weight conversion (one-time). n8 = elements/8.
// -------------------------------------------------------------------------
__global__ __launch_bounds__(256) void wcvt(
    const float* __restrict__ src, unsigned short* __restrict__ dst, int n8) {
  int i = blockIdx.x * 256 + threadIdx.x;
  if (i >= n8) return;
  const float* p = src + (size_t)i * 8;
  floatx4 a = *(const floatx4*)p;
  floatx4 b = *(const floatx4*)(p + 4);
  short8 o;
#pragma unroll
  for (int k = 0; k < 4; ++k) { o[k] = (short)f2bf(a[k]); o[k + 4] = (short)f2bf(b[k]); }
  *(short8*)(dst + (size_t)i * 8) = o;
}

// -------------------------------------------------------------------------
// LN1 + roll(-3,-3) + window-partition gather, fp32 -> bf16.
// -------------------------------------------------------------------------
__global__ __launch_bounds__(256) void prep_ln1(
    const float* __restrict__ x1, const float* __restrict__ g,
    const float* __restrict__ b, unsigned short* __restrict__ a1w) {
  int gw = (blockIdx.x * 256 + threadIdx.x) >> 6;
  int lane = threadIdx.x & 63;
  if (gw >= TOKENS) return;
  int n = gw % 49, w = gw / 49;
  int i = n / 7, j = n % 7;
  int ww = w & 7, wh = (w >> 3) & 7, bb = w >> 6;
  int hs = (wh * 7 + i + 3) % 56;
  int wsS = (ww * 7 + j + 3) % 56;
  const float* rp = x1 + ((size_t)bb * 3136 + (size_t)hs * 56 + wsS) * 512 + lane * 8;
  floatx4 a0 = *(const floatx4*)rp;
  floatx4 a1 = *(const floatx4*)(rp + 4);
  float s = 0.f, ss = 0.f;
#pragma unroll
  for (int k = 0; k < 4; ++k) { s += a0[k]; ss += a0[k] * a0[k]; }
#pragma unroll
  for (int k = 0; k < 4; ++k) { s += a1[k]; ss += a1[k] * a1[k]; }
  for (int m = 32; m >= 1; m >>= 1) {
    s  += __shfl_xor(s, m, 64);
    ss += __shfl_xor(ss, m, 64);
  }
  float mu = s * (1.f / 512.f);
  float var = ss * (1.f / 512.f) - mu * mu;
  float rstd = rsqrtf(var + 1e-5f);
  floatx4 g0 = *(const floatx4*)(g + lane * 8);
  floatx4 g1 = *(const floatx4*)(g + lane * 8 + 4);
  floatx4 b0 = *(const floatx4*)(b + lane * 8);
  floatx4 b1 = *(const floatx4*)(b + lane * 8 + 4);
  short8 o8;
#pragma unroll
  for (int k = 0; k < 4; ++k) {
    o8[k]     = (short)f2bf((a0[k] - mu) * rstd * g0[k] + b0[k]);
    o8[k + 4] = (short)f2bf((a1[k] - mu) * rstd * g1[k] + b1[k]);
  }
  *(short8*)(a1w + (size_t)gw * 512 + lane * 8) = o8;
}

// -------------------------------------------------------------------------
// LN2 full apply: fp32 row -> normalized bf16 row. One wave per token.
// -------------------------------------------------------------------------
__global__ __launch_bounds__(256) void ln2_apply(
    const float* __restrict__ xin, const float* __restrict__ g,
    const float* __restrict__ b, unsigned short* __restrict__ outb) {
  int gw = (blockIdx.x * 256 + threadIdx.x) >> 6;
  int lane = threadIdx.x & 63;
  if (gw >= TOKENS) return;
  const float* rp = xin + (size_t)gw * 512 + lane * 8;
  floatx4 a0 = *(const floatx4*)rp;
  floatx4 a1 = *(const floatx4*)(rp + 4);
  float s = 0.f, ss = 0.f;
#pragma unroll
  for (int k = 0; k < 4; ++k) { s += a0[k]; ss += a0[k] * a0[k]; }
#pragma unroll
  for (int k = 0; k < 4; ++k) { s += a1[k]; ss += a1[k] * a1[k]; }
  for (int m = 32; m >= 1; m >>= 1) {
    s  += __shfl_xor(s, m, 64);
    ss += __shfl_xor(ss, m, 64);
  }
  float mu = s * (1.f / 512.f);
  float var = ss * (1.f / 512.f) - mu * mu;
  float rstd = rsqrtf(var + 1e-5f);
  floatx4 g0 = *(const floatx4*)(g + lane * 8);
  floatx4 g1 = *(const floatx4*)(g + lane * 8 + 4);
  floatx4 b0 = *(const floatx4*)(b + lane * 8);
  floatx4 b1 = *(const floatx4*)(b + lane * 8 + 4);
  short8 o8;
#pragma unroll
  for (int k = 0; k < 4; ++k) {
    o8[k]     = (short)f2bf((a0[k] - mu) * rstd * g0[k] + b0[k]);
    o8[k + 4] = (short)f2bf((a1[k] - mu) * rstd * g1[k] + b1[k]);
  }
  *(short8*)(outb + (size_t)gw * 512 + lane * 8) = o8;
}

// -------------------------------------------------------------------------
// m97-structure GEMM (unchanged).
// -------------------------------------------------------------------------
template <int EPI>
__global__ __launch_bounds__(256, 2) void gemm_glds(
    const unsigned short* __restrict__ A,
    const unsigned short* __restrict__ Bw,
    const float* __restrict__ bias,
    void* __restrict__ outp,
    const float* __restrict__ res,
    int N, int K, int lda) {
  __shared__ unsigned short lA[128 * 64];
  __shared__ unsigned short lB[128 * 64];
  int tid = threadIdx.x;
  int wave = tid >> 6, lane = tid & 63;

  int srow = wave * 32 + (lane >> 3);
  int scol = (lane & 7) * 8;
  const unsigned short* gA[4];
  const unsigned short* gB[4];
#pragma unroll
  for (int i = 0; i < 4; ++i) {
    gA[i] = A + (size_t)(blockIdx.x * 128 + srow + i * 8) * lda + scol;
    gB[i] = Bw + (size_t)(blockIdx.y * 128 + srow + i * 8) * K + scol;
  }
  unsigned short* lAp = &lA[wave * 2048];
  unsigned short* lBp = &lB[wave * 2048];

  int wm = (wave >> 1) * 64, wn = (wave & 1) * 64;
  int l15 = lane & 15, kq = (lane >> 4) * 8;
  int KT = K >> 6;
  floatx4 acc[4][4] = {};

  for (int kt = 0; kt < KT; ++kt) {
    int ko = kt * 64;
#pragma unroll
    for (int i = 0; i < 4; ++i) {
      gload16(gA[i] + ko, lAp + i * 512);
      gload16(gB[i] + ko, lBp + i * 512);
    }
    __syncthreads();
#pragma unroll
    for (int ks = 0; ks < 2; ++ks) {
      short8 af[4], bf8[4];
#pragma unroll
      for (int tm = 0; tm < 4; ++tm)
        af[tm] = *(const short8*)&lA[(wm + tm * 16 + l15) * 64 + ks * 32 + kq];
#pragma unroll
      for (int tn = 0; tn < 4; ++tn)
        bf8[tn] = *(const short8*)&lB[(wn + tn * 16 + l15) * 64 + ks * 32 + kq];
#pragma unroll
      for (int tm = 0; tm < 4; ++tm)
#pragma unroll
        for (int tn = 0; tn < 4; ++tn)
          acc[tm][tn] = __builtin_amdgcn_mfma_f32_16x16x32_bf16(
              af[tm], bf8[tn], acc[tm][tn], 0, 0, 0);
    }
    __syncthreads();
  }

  int colb = blockIdx.y * 128 + wn + l15;
  int rowb = blockIdx.x * 128 + wm + ((lane >> 4) << 2);
#pragma unroll
  for (int tm = 0; tm < 4; ++tm) {
#pragma unroll
    for (int rg = 0; rg < 4; ++rg) {
      int m = rowb + tm * 16 + rg;
      size_t outrow;
      const float* resrow = nullptr;
      if (EPI == 1) {
        int nn = m % 49, wI = m / 49;
        int i = nn / 7, j = nn % 7;
        int wwI = wI & 7, whI = (wI >> 3) & 7, bb = wI >> 6;
        int hs = (whI * 7 + i + 3) % 56;
        int wsS = (wwI * 7 + j + 3) % 56;
        size_t orig = (size_t)bb * 3136 + (size_t)hs * 56 + wsS;
        outrow = orig * 512;
        resrow = res + orig * 512;
      } else {
        outrow = (size_t)m * N;
        if (EPI == 3) resrow = res + (size_t)m * 512;
      }
#pragma unroll
      for (int tn = 0; tn < 4; ++tn) {
        int n = colb + tn * 16;
        float v = acc[tm][tn][rg] + bias[n];
        if (EPI == 2) v = 0.5f * v * (1.f + erff(v * 0.70710678118654752f));
        if (EPI == 0 || EPI == 2) {
          ((unsigned short*)outp)[outrow + n] = f2bf(v);
        } else {
          ((float*)outp)[outrow + n] = v + resrow[n];
        }
      }
    }
  }
}

// -------------------------------------------------------------------------
// MFMA windowed attention. One wave = one (window, head). Grid 4096 = 1024
// windows x 4 head-groups; 4 waves/block, no barriers (LDS wave-private).
// S^T = mfma(K, Q): A/B frags direct from global. Softmax per q-column:
// 16 in-lane + shfl_xor(16,32). P (normalized bf16) -> LDS A-layout with
// XOR swizzle. V reg-staged from global, written TRANSPOSED to Vt[32][72]
// (d-major, pad 72 = GEMM-proven); PV B-frags via plain ds_read_b128.
// O = P*V stored in place into the Q columns.
// -------------------------------------------------------------------------
__global__ __launch_bounds__(256, 3) void attn_mfma(
    unsigned short* qkv,                      // (1024*49, 1536) bf16, in/out
    const float* __restrict__ relt) {         // (169,16) fp32
  __shared__ unsigned short ldsVt[4][32 * 72];  // [wave][d][k] transposed V
  __shared__ unsigned short ldsP[4][4096];      // [wave][q*64 + k] swizzled
  int wave = threadIdx.x >> 6, lane = threadIdx.x & 63;
  int win = blockIdx.x >> 2, hg = blockIdx.x & 3;
  int head = hg * 4 + wave;
  int l15 = lane & 15, rg = lane >> 4;
  int wh = (win >> 3) & 7, ww = win & 7;
  const size_t base = (size_t)win * 49 * 1536;

  // ---- V reg-stage (global loads issued early; latency hides under QK) ----
  short8 vreg[4];
#pragma unroll
  for (int c = 0; c < 4; ++c) {
    int p = c >> 1, kh = c & 1;
    int k = kh * 32 + (lane >> 1);
    int kr = k < 49 ? k : 48;
    vreg[c] = *(const short8*)(qkv + base + (size_t)kr * 1536 + head * 32 +
                               1024 + p * 16 + (lane & 1) * 8);
  }

  // ---- geometry precompute (head-independent) ----
  int iq[4], jq[4], rq[4];
#pragma unroll
  for (int tn = 0; tn < 4; ++tn) {
    int q = tn * 16 + l15;
    int i7 = (q * 9363) >> 16;
    iq[tn] = i7; jq[tn] = q - i7 * 7;
    int rh = (wh < 7) ? 0 : ((i7 < 4) ? 1 : 2);
    int rw = (ww < 7) ? 0 : ((jq[tn] < 4) ? 1 : 2);
    rq[tn] = rh * 3 + rw;
  }
  unsigned ridx4[16];
  unsigned long long mbits = 0ull;
  unsigned validb = 0;
#pragma unroll
  for (int tm = 0; tm < 4; ++tm) {
#pragma unroll
    for (int rr = 0; rr < 4; ++rr) {
      int e = tm * 4 + rr;
      int k = tm * 16 + rg * 4 + rr;
      int ik = (k * 9363) >> 16;
      int jk = k - ik * 7;
      int rhk = (wh < 7) ? 0 : ((ik < 4) ? 1 : 2);
      int rwk = (ww < 7) ? 0 : ((jk < 4) ? 1 : 2);
      int rk = rhk * 3 + rwk;
      if (k < 49) validb |= (1u << e);
      unsigned pack = 0;
#pragma unroll
      for (int tn = 0; tn < 4; ++tn) {
        int ridx = (iq[tn] - ik + 6) * 13 + (jq[tn] - jk + 6);
        ridx = ridx < 0 ? 0 : (ridx > 168 ? 168 : ridx);
        pack |= (unsigned)ridx << (8 * tn);
        if (rq[tn] != rk) mbits |= 1ull << (e * 4 + tn);
      }
      ridx4[e] = pack;
    }
  }

  // ---- QK^T (swapped): S^T tiles, frags direct from global ----
  short8 kf[4], qf[4];
#pragma unroll
  for (int t = 0; t < 4; ++t) {
    int r = t * 16 + l15; r = r < 49 ? r : 48;
    kf[t] = *(const short8*)(qkv + base + (size_t)r * 1536 + head * 32 + 512 + rg * 8);
    qf[t] = *(const short8*)(qkv + base + (size_t)r * 1536 + head * 32 + rg * 8);
  }
  floatx4 acc[4][4] = {};
#pragma unroll
  for (int tm = 0; tm < 4; ++tm)
#pragma unroll
    for (int tn = 0; tn < 4; ++tn)
      acc[tm][tn] = __builtin_amdgcn_mfma_f32_16x16x32_bf16(
          kf[tm], qf[tn], acc[tm][tn], 0, 0, 0);

  // ---- V -> LDS transposed: Vt[d][k], d-major, row stride 72 ----
  unsigned short* vt = &ldsVt[wave][0];
#pragma unroll
  for (int c = 0; c < 4; ++c) {
    int p = c >> 1, kh = c & 1;
    int k = kh * 32 + (lane >> 1);
    int d0 = p * 16 + (lane & 1) * 8;
#pragma unroll
    for (int j = 0; j < 8; ++j)
      vt[(d0 + j) * 72 + k] = (unsigned short)vreg[c][j];
  }

  // ---- scale + bias + mask, per-q-column max ----
  float mrow[4] = {-3e38f, -3e38f, -3e38f, -3e38f};
#pragma unroll
  for (int tm = 0; tm < 4; ++tm) {
#pragma unroll
    for (int rr = 0; rr < 4; ++rr) {
      int e = tm * 4 + rr;
      bool val = (validb >> e) & 1;
#pragma unroll
      for (int tn = 0; tn < 4; ++tn) {
        float bias = relt[((ridx4[e] >> (8 * tn)) & 255u) * 16 + head];
        float mk = ((mbits >> (e * 4 + tn)) & 1ull) ? -100.f : 0.f;
        float v = val ? fmaf(acc[tm][tn][rr], 0.17677669529663687f, bias + mk)
                      : -1e30f;
        acc[tm][tn][rr] = v;
        mrow[tn] = fmaxf(mrow[tn], v);
      }
    }
  }
#pragma unroll
  for (int tn = 0; tn < 4; ++tn) {
    mrow[tn] = fmaxf(mrow[tn], __shfl_xor(mrow[tn], 16, 64));
    mrow[tn] = fmaxf(mrow[tn], __shfl_xor(mrow[tn], 32, 64));
  }
  // ---- exp + sum ----
  float ssum[4] = {0.f, 0.f, 0.f, 0.f};
#pragma unroll
  for (int tm = 0; tm < 4; ++tm)
#pragma unroll
    for (int tn = 0; tn < 4; ++tn)
#pragma unroll
      for (int rr = 0; rr < 4; ++rr) {
        float e = __expf(acc[tm][tn][rr] - mrow[tn]);
        acc[tm][tn][rr] = e;
        ssum[tn] += e;
      }
#pragma unroll
  for (int tn = 0; tn < 4; ++tn) {
    ssum[tn] += __shfl_xor(ssum[tn], 16, 64);
    ssum[tn] += __shfl_xor(ssum[tn], 32, 64);
  }
  float inv[4];
#pragma unroll
  for (int tn = 0; tn < 4; ++tn) inv[tn] = 1.f / ssum[tn];

  // ---- P (normalized) -> LDS, A-layout [q][k] bf16, swizzle ^((q&7)<<4) ----
  char* pb = (char*)&ldsP[wave][0];
#pragma unroll
  for (int tm = 0; tm < 4; ++tm) {
#pragma unroll
    for (int tn = 0; tn < 4; ++tn) {
      unsigned lo = cvtpk(acc[tm][tn][0] * inv[tn], acc[tm][tn][1] * inv[tn]);
      unsigned hi = cvtpk(acc[tm][tn][2] * inv[tn], acc[tm][tn][3] * inv[tn]);
      int q = tn * 16 + l15;
      int off = (q * 128 + tm * 32 + rg * 8) ^ ((q & 7) << 4);
      *(unsigned long long*)(pb + off) = ((unsigned long long)hi << 32) | lo;
    }
  }

  // ---- PV: O = P*V (A = P from swizzled LDS, B = Vt rows, plain b128) ----
  floatx4 o[4][2] = {};
#pragma unroll
  for (int ks = 0; ks < 2; ++ks) {
    short8 af[4], vf[2];
#pragma unroll
    for (int qt = 0; qt < 4; ++qt) {
      int q = qt * 16 + l15;
      int off = (q * 128 + ks * 64 + rg * 16) ^ ((q & 7) << 4);
      af[qt] = *(const short8*)(pb + off);
    }
#pragma unroll
    for (int dt = 0; dt < 2; ++dt)
      vf[dt] = *(const short8*)&ldsVt[wave][(dt * 16 + l15) * 72 + ks * 32 + rg * 8];
#pragma unroll
    for (int qt = 0; qt < 4; ++qt)
#pragma unroll
      for (int dt = 0; dt < 2; ++dt)
        o[qt][dt] = __builtin_amdgcn_mfma_f32_16x16x32_bf16(
            af[qt], vf[dt], o[qt][dt], 0, 0, 0);
  }

  // ---- store O in place into Q columns (rows q<49) ----
#pragma unroll
  for (int qt = 0; qt < 4; ++qt) {
#pragma unroll
    for (int rr = 0; rr < 4; ++rr) {
      int q = qt * 16 + rg * 4 + rr;
      if (q < 49) {
#pragma unroll
        for (int dt = 0; dt < 2; ++dt)
          qkv[base + (size_t)q * 1536 + head * 32 + dt * 16 + l15] =
              f2bf(o[qt][dt][rr]);
      }
    }
  }
}

// -------------------------------------------------------------------------
extern "C" void kernel_launch(void* const* d_in, const int* in_sizes, int n_in,
                              void* d_out, int out_size, void* d_ws, size_t ws_size,
                              hipStream_t stream) {
  const float* x1     = (const float*)d_in[0];
  // d_in[1] = x2 : dead code in reference (xw[:,:,:C] uses only the x1 branch)
  const float* n1g    = (const float*)d_in[2];
  const float* n1b    = (const float*)d_in[3];
  const float* qkv_w  = (const float*)d_in[4];
  const float* qkv_b  = (const float*)d_in[5];
  const float* rel_t  = (const float*)d_in[6];
  const float* proj_w = (const float*)d_in[7];
  const float* proj_b = (const float*)d_in[8];
  const float* n2g    = (const float*)d_in[9];
  const float* n2b    = (const float*)d_in[10];
  const float* fc1_w  = (const float*)d_in[11];
  const float* fc1_b  = (const float*)d_in[12];
  const float* fc2_w  = (const float*)d_in[13];
  const float* fc2_b  = (const float*)d_in[14];
  float* outp = (float*)d_out;   // fp32; also holds x (residual-1 result)

  // ws layout (205,922,304 B), phase-aware:
  //  phase A: a1w [0..51,380,224) | bufQ [51,380,224..205,520,896)
  //  after QKV (a1w dead): pwbf | f1wbf | f2wbf
  //  after proj (bufQ dead): xln2 | hbuf
  //  qkv_wbf parks in d_out (dead until proj writes it).
  char* ws = (char*)d_ws;
  unsigned short* a1w    = (unsigned short*)ws;
  unsigned short* bufQ   = (unsigned short*)(ws + 51380224);
  unsigned short* pwbf   = (unsigned short*)ws;
  unsigned short* f1wbf  = (unsigned short*)(ws + 524288);
  unsigned short* f2wbf  = (unsigned short*)(ws + 2621440);
  unsigned short* xln2   = (unsigned short*)(ws + 4718592);
  unsigned short* hbuf   = (unsigned short*)(ws + 56098816);
  unsigned short* qkvwbf = (unsigned short*)d_out;

  wcvt<<<384, 256, 0, stream>>>(qkv_w, qkvwbf, 98304);
  prep_ln1<<<TOKENS / 4, 256, 0, stream>>>(x1, n1g, n1b, a1w);
  gemm_glds<0><<<dim3(392, 12), 256, 0, stream>>>(
      a1w, qkvwbf, qkv_b, bufQ, nullptr, 1536, 512, 512);
  wcvt<<<128, 256, 0, stream>>>(proj_w, pwbf, 32768);
  wcvt<<<512, 256, 0, stream>>>(fc1_w, f1wbf, 131072);
  wcvt<<<512, 256, 0, stream>>>(fc2_w, f2wbf, 131072);
  attn_mfma<<<4096, 256, 0, stream>>>(bufQ, rel_t);
  gemm_glds<1><<<dim3(392, 4), 256, 0, stream>>>(
      bufQ, pwbf, proj_b, outp, x1, 512, 512, 1536);
  ln2_apply<<<TOKENS / 4, 256, 0, stream>>>(outp, n2g, n2b, xln2);
  for (int ch = 0; ch < 2; ++ch) {
    size_t ro = (size_t)ch * HTOK * 512;
    gemm_glds<2><<<dim3(196, 16), 256, 0, stream>>>(
        xln2 + ro, f1wbf, fc1_b, hbuf, nullptr, 2048, 512, 512);
    gemm_glds<3><<<dim3(196, 4), 256, 0, stream>>>(
        hbuf, f2wbf, fc2_b, outp + ro, outp + ro, 512, 2048, 2048);
  }
}

// Round 5
// 915.208 us; speedup vs baseline: 1.5004x; 1.0820x over previous
//
#include <hip/hip_runtime.h>
#include <math.h>

typedef __attribute__((ext_vector_type(8))) short short8;
typedef __attribute__((ext_vector_type(4))) float floatx4;

#define TOKENS 50176   // 16 * 64 windows * 49
#define HTOK   25088   // TOKENS/2 (fc1/fc2 row chunk)

__device__ __forceinline__ unsigned short f2bf(float f) {
  union { float f; unsigned int i; } x; x.f = f;
  unsigned int r = x.i + 0x7fffu + ((x.i >> 16) & 1u);
  return (unsigned short)(r >> 16);
}
__device__ __forceinline__ float bf2f(unsigned short u) {
  union { unsigned int i; float f; } x; x.i = ((unsigned int)u) << 16; return x.f;
}

// async global->LDS, 16B per lane; LDS dest = wave-uniform base + lane*16
__device__ __forceinline__ void gload16(const void* g, void* l) {
  __builtin_amdgcn_global_load_lds(
      (__attribute__((address_space(1))) void*)g,
      (__attribute__((address_space(3))) void*)l, 16, 0, 0);
}

__device__ __forceinline__ unsigned cvtpk(float lo, float hi) {
  unsigned r;
  asm("v_cvt_pk_bf16_f32 %0, %1, %2" : "=v"(r) : "v"(lo), "v"(hi));
  return r;
}

// -------------------------------------------------------------------------
// fp32 -> bf16 weight conversion (one-time). n8 = elements/8.
// -------------------------------------------------------------------------
__global__ __launch_bounds__(256) void wcvt(
    const float* __restrict__ src, unsigned short* __restrict__ dst, int n8) {
  int i = blockIdx.x * 256 + threadIdx.x;
  if (i >= n8) return;
  const float* p = src + (size_t)i * 8;
  floatx4 a = *(const floatx4*)p;
  floatx4 b = *(const floatx4*)(p + 4);
  short8 o;
#pragma unroll
  for (int k = 0; k < 4; ++k) { o[k] = (short)f2bf(a[k]); o[k + 4] = (short)f2bf(b[k]); }
  *(short8*)(dst + (size_t)i * 8) = o;
}

// -------------------------------------------------------------------------
// Combined rel-bias + shift-mask table: btab[cls][head][q(64)][k(64)] fp32.
// cls = (wh==7)*2 + (ww==7). k>=49 rows poisoned with -1e30 (valid-mask).
// One-time, 262144 threads.
// -------------------------------------------------------------------------
__global__ __launch_bounds__(256) void btab_build(
    const float* __restrict__ relt, float* __restrict__ btab) {
  int idx = blockIdx.x * 256 + threadIdx.x;   // 4*16*64*64 = 262144
  int k = idx & 63;
  int q = (idx >> 6) & 63;
  int head = (idx >> 12) & 15;
  int cls = idx >> 16;
  float v;
  if (k >= 49) {
    v = -1e30f;
  } else if (q >= 49) {
    v = 0.f;
  } else {
    int iq = q / 7, jq = q % 7, ik = k / 7, jk = k % 7;
    int clsH = cls >> 1, clsW = cls & 1;
    int rq = (clsH ? ((iq < 4) ? 1 : 2) : 0) * 3 + (clsW ? ((jq < 4) ? 1 : 2) : 0);
    int rk = (clsH ? ((ik < 4) ? 1 : 2) : 0) * 3 + (clsW ? ((jk < 4) ? 1 : 2) : 0);
    int ridx = (iq - ik + 6) * 13 + (jq - jk + 6);
    v = relt[ridx * 16 + head] + ((rq != rk) ? -100.f : 0.f);
  }
  btab[idx] = v;
}

// -------------------------------------------------------------------------
// LN1 + roll(-3,-3) + window-partition gather, fp32 -> bf16.
// -------------------------------------------------------------------------
__global__ __launch_bounds__(256) void prep_ln1(
    const float* __restrict__ x1, const float* __restrict__ g,
    const float* __restrict__ b, unsigned short* __restrict__ a1w) {
  int gw = (blockIdx.x * 256 + threadIdx.x) >> 6;
  int lane = threadIdx.x & 63;
  if (gw >= TOKENS) return;
  int n = gw % 49, w = gw / 49;
  int i = n / 7, j = n % 7;
  int ww = w & 7, wh = (w >> 3) & 7, bb = w >> 6;
  int hs = (wh * 7 + i + 3) % 56;
  int wsS = (ww * 7 + j + 3) % 56;
  const float* rp = x1 + ((size_t)bb * 3136 + (size_t)hs * 56 + wsS) * 512 + lane * 8;
  floatx4 a0 = *(const floatx4*)rp;
  floatx4 a1 = *(const floatx4*)(rp + 4);
  float s = 0.f, ss = 0.f;
#pragma unroll
  for (int k = 0; k < 4; ++k) { s += a0[k]; ss += a0[k] * a0[k]; }
#pragma unroll
  for (int k = 0; k < 4; ++k) { s += a1[k]; ss += a1[k] * a1[k]; }
  for (int m = 32; m >= 1; m >>= 1) {
    s  += __shfl_xor(s, m, 64);
    ss += __shfl_xor(ss, m, 64);
  }
  float mu = s * (1.f / 512.f);
  float var = ss * (1.f / 512.f) - mu * mu;
  float rstd = rsqrtf(var + 1e-5f);
  floatx4 g0 = *(const floatx4*)(g + lane * 8);
  floatx4 g1 = *(const floatx4*)(g + lane * 8 + 4);
  floatx4 b0 = *(const floatx4*)(b + lane * 8);
  floatx4 b1 = *(const floatx4*)(b + lane * 8 + 4);
  short8 o8;
#pragma unroll
  for (int k = 0; k < 4; ++k) {
    o8[k]     = (short)f2bf((a0[k] - mu) * rstd * g0[k] + b0[k]);
    o8[k + 4] = (short)f2bf((a1[k] - mu) * rstd * g1[k] + b1[k]);
  }
  *(short8*)(a1w + (size_t)gw * 512 + lane * 8) = o8;
}

// -------------------------------------------------------------------------
// LN2 full apply: fp32 row -> normalized bf16 row. One wave per token.
// -------------------------------------------------------------------------
__global__ __launch_bounds__(256) void ln2_apply(
    const float* __restrict__ xin, const float* __restrict__ g,
    const float* __restrict__ b, unsigned short* __restrict__ outb) {
  int gw = (blockIdx.x * 256 + threadIdx.x) >> 6;
  int lane = threadIdx.x & 63;
  if (gw >= TOKENS) return;
  const float* rp = xin + (size_t)gw * 512 + lane * 8;
  floatx4 a0 = *(const floatx4*)rp;
  floatx4 a1 = *(const floatx4*)(rp + 4);
  float s = 0.f, ss = 0.f;
#pragma unroll
  for (int k = 0; k < 4; ++k) { s += a0[k]; ss += a0[k] * a0[k]; }
#pragma unroll
  for (int k = 0; k < 4; ++k) { s += a1[k]; ss += a1[k] * a1[k]; }
  for (int m = 32; m >= 1; m >>= 1) {
    s  += __shfl_xor(s, m, 64);
    ss += __shfl_xor(ss, m, 64);
  }
  float mu = s * (1.f / 512.f);
  float var = ss * (1.f / 512.f) - mu * mu;
  float rstd = rsqrtf(var + 1e-5f);
  floatx4 g0 = *(const floatx4*)(g + lane * 8);
  floatx4 g1 = *(const floatx4*)(g + lane * 8 + 4);
  floatx4 b0 = *(const floatx4*)(b + lane * 8);
  floatx4 b1 = *(const floatx4*)(b + lane * 8 + 4);
  short8 o8;
#pragma unroll
  for (int k = 0; k < 4; ++k) {
    o8[k]     = (short)f2bf((a0[k] - mu) * rstd * g0[k] + b0[k]);
    o8[k + 4] = (short)f2bf((a1[k] - mu) * rstd * g1[k] + b1[k]);
  }
  *(short8*)(outb + (size_t)gw * 512 + lane * 8) = o8;
}

// -------------------------------------------------------------------------
// m97-structure GEMM. EPI 0 additionally folds the attention SCALE into the
// Q columns (n<512) — only the QKV call uses EPI 0.
// -------------------------------------------------------------------------
template <int EPI>
__global__ __launch_bounds__(256, 2) void gemm_glds(
    const unsigned short* __restrict__ A,
    const unsigned short* __restrict__ Bw,
    const float* __restrict__ bias,
    void* __restrict__ outp,
    const float* __restrict__ res,
    int N, int K, int lda) {
  __shared__ unsigned short lA[128 * 64];
  __shared__ unsigned short lB[128 * 64];
  int tid = threadIdx.x;
  int wave = tid >> 6, lane = tid & 63;

  int srow = wave * 32 + (lane >> 3);
  int scol = (lane & 7) * 8;
  const unsigned short* gA[4];
  const unsigned short* gB[4];
#pragma unroll
  for (int i = 0; i < 4; ++i) {
    gA[i] = A + (size_t)(blockIdx.x * 128 + srow + i * 8) * lda + scol;
    gB[i] = Bw + (size_t)(blockIdx.y * 128 + srow + i * 8) * K + scol;
  }
  unsigned short* lAp = &lA[wave * 2048];
  unsigned short* lBp = &lB[wave * 2048];

  int wm = (wave >> 1) * 64, wn = (wave & 1) * 64;
  int l15 = lane & 15, kq = (lane >> 4) * 8;
  int KT = K >> 6;
  floatx4 acc[4][4] = {};

  for (int kt = 0; kt < KT; ++kt) {
    int ko = kt * 64;
#pragma unroll
    for (int i = 0; i < 4; ++i) {
      gload16(gA[i] + ko, lAp + i * 512);
      gload16(gB[i] + ko, lBp + i * 512);
    }
    __syncthreads();
#pragma unroll
    for (int ks = 0; ks < 2; ++ks) {
      short8 af[4], bf8[4];
#pragma unroll
      for (int tm = 0; tm < 4; ++tm)
        af[tm] = *(const short8*)&lA[(wm + tm * 16 + l15) * 64 + ks * 32 + kq];
#pragma unroll
      for (int tn = 0; tn < 4; ++tn)
        bf8[tn] = *(const short8*)&lB[(wn + tn * 16 + l15) * 64 + ks * 32 + kq];
#pragma unroll
      for (int tm = 0; tm < 4; ++tm)
#pragma unroll
        for (int tn = 0; tn < 4; ++tn)
          acc[tm][tn] = __builtin_amdgcn_mfma_f32_16x16x32_bf16(
              af[tm], bf8[tn], acc[tm][tn], 0, 0, 0);
    }
    __syncthreads();
  }

  int colb = blockIdx.y * 128 + wn + l15;
  int rowb = blockIdx.x * 128 + wm + ((lane >> 4) << 2);
#pragma unroll
  for (int tm = 0; tm < 4; ++tm) {
#pragma unroll
    for (int rg = 0; rg < 4; ++rg) {
      int m = rowb + tm * 16 + rg;
      size_t outrow;
      const float* resrow = nullptr;
      if (EPI == 1) {
        int nn = m % 49, wI = m / 49;
        int i = nn / 7, j = nn % 7;
        int wwI = wI & 7, whI = (wI >> 3) & 7, bb = wI >> 6;
        int hs = (whI * 7 + i + 3) % 56;
        int wsS = (wwI * 7 + j + 3) % 56;
        size_t orig = (size_t)bb * 3136 + (size_t)hs * 56 + wsS;
        outrow = orig * 512;
        resrow = res + orig * 512;
      } else {
        outrow = (size_t)m * N;
        if (EPI == 3) resrow = res + (size_t)m * 512;
      }
#pragma unroll
      for (int tn = 0; tn < 4; ++tn) {
        int n = colb + tn * 16;
        float v = acc[tm][tn][rg] + bias[n];
        if (EPI == 0 && n < 512) v *= 0.17677669529663687f;  // SCALE on Q cols
        if (EPI == 2) v = 0.5f * v * (1.f + erff(v * 0.70710678118654752f));
        if (EPI == 0 || EPI == 2) {
          ((unsigned short*)outp)[outrow + n] = f2bf(v);
        } else {
          ((float*)outp)[outrow + n] = v + resrow[n];
        }
      }
    }
  }
}

// -------------------------------------------------------------------------
// MFMA windowed attention. One wave = one (window, head). Grid 4096 = 1024
// windows x 4 head-groups; 4 waves/block, no barriers (LDS wave-private).
// S^T = mfma(K, Q): frags direct from global (Q pre-scaled in QKV epilogue).
// Bias+mask from precomputed btab[cls][head][q][k] (fp32, vectorized loads).
// Softmax per q-column: 16 in-lane + shfl_xor(16,32). P (normalized bf16)
// -> LDS A-layout with XOR swizzle. V reg-staged, written transposed to
// Vt[32][72]; PV B-frags via plain ds_read_b128. O stored in place into Q.
// -------------------------------------------------------------------------
__global__ __launch_bounds__(256, 3) void attn_mfma(
    unsigned short* qkv,                      // (1024*49, 1536) bf16, in/out
    const float* __restrict__ btab) {         // (4,16,64,64) fp32
  __shared__ unsigned short ldsVt[4][32 * 72];  // [wave][d][k] transposed V
  __shared__ unsigned short ldsP[4][4096];      // [wave][q*64 + k] swizzled
  int wave = threadIdx.x >> 6, lane = threadIdx.x & 63;
  int win = blockIdx.x >> 2, hg = blockIdx.x & 3;
  int head = hg * 4 + wave;
  int l15 = lane & 15, rg = lane >> 4;
  int wh = (win >> 3) & 7, ww = win & 7;
  int cls = (((wh == 7) ? 1 : 0) << 1) | ((ww == 7) ? 1 : 0);
  const size_t base = (size_t)win * 49 * 1536;
  const float* bt = btab + ((size_t)(cls * 16 + head) << 12);

  // ---- V reg-stage (global loads issued early; latency hides under QK) ----
  short8 vreg[4];
#pragma unroll
  for (int c = 0; c < 4; ++c) {
    int p = c >> 1, kh = c & 1;
    int k = kh * 32 + (lane >> 1);
    int kr = k < 49 ? k : 48;
    vreg[c] = *(const short8*)(qkv + base + (size_t)kr * 1536 + head * 32 +
                               1024 + p * 16 + (lane & 1) * 8);
  }

  // ---- QK^T (swapped): S^T tiles, frags direct from global ----
  short8 kf[4], qf[4];
#pragma unroll
  for (int t = 0; t < 4; ++t) {
    int r = t * 16 + l15; r = r < 49 ? r : 48;
    kf[t] = *(const short8*)(qkv + base + (size_t)r * 1536 + head * 32 + 512 + rg * 8);
    qf[t] = *(const short8*)(qkv + base + (size_t)r * 1536 + head * 32 + rg * 8);
  }
  floatx4 acc[4][4] = {};
#pragma unroll
  for (int tm = 0; tm < 4; ++tm)
#pragma unroll
    for (int tn = 0; tn < 4; ++tn)
      acc[tm][tn] = __builtin_amdgcn_mfma_f32_16x16x32_bf16(
          kf[tm], qf[tn], acc[tm][tn], 0, 0, 0);

  // ---- V -> LDS transposed: Vt[d][k], d-major, row stride 72 ----
  unsigned short* vt = &ldsVt[wave][0];
#pragma unroll
  for (int c = 0; c < 4; ++c) {
    int p = c >> 1, kh = c & 1;
    int k = kh * 32 + (lane >> 1);
    int d0 = p * 16 + (lane & 1) * 8;
#pragma unroll
    for (int j = 0; j < 8; ++j)
      vt[(d0 + j) * 72 + k] = (unsigned short)vreg[c][j];
  }

  // ---- + btab (bias+mask+valid fused), per-q-column max ----
  float mrow[4] = {-3e38f, -3e38f, -3e38f, -3e38f};
#pragma unroll
  for (int tn = 0; tn < 4; ++tn) {
    const float* btq = bt + (size_t)(tn * 16 + l15) * 64 + rg * 4;
#pragma unroll
    for (int tm = 0; tm < 4; ++tm) {
      floatx4 bv = *(const floatx4*)(btq + tm * 16);
#pragma unroll
      for (int rr = 0; rr < 4; ++rr) {
        float v = acc[tm][tn][rr] + bv[rr];
        acc[tm][tn][rr] = v;
        mrow[tn] = fmaxf(mrow[tn], v);
      }
    }
  }
#pragma unroll
  for (int tn = 0; tn < 4; ++tn) {
    mrow[tn] = fmaxf(mrow[tn], __shfl_xor(mrow[tn], 16, 64));
    mrow[tn] = fmaxf(mrow[tn], __shfl_xor(mrow[tn], 32, 64));
  }
  // ---- exp + sum ----
  float ssum[4] = {0.f, 0.f, 0.f, 0.f};
#pragma unroll
  for (int tm = 0; tm < 4; ++tm)
#pragma unroll
    for (int tn = 0; tn < 4; ++tn)
#pragma unroll
      for (int rr = 0; rr < 4; ++rr) {
        float e = __expf(acc[tm][tn][rr] - mrow[tn]);
        acc[tm][tn][rr] = e;
        ssum[tn] += e;
      }
#pragma unroll
  for (int tn = 0; tn < 4; ++tn) {
    ssum[tn] += __shfl_xor(ssum[tn], 16, 64);
    ssum[tn] += __shfl_xor(ssum[tn], 32, 64);
  }
  float inv[4];
#pragma unroll
  for (int tn = 0; tn < 4; ++tn) inv[tn] = 1.f / ssum[tn];

  // ---- P (normalized) -> LDS, A-layout [q][k] bf16, swizzle ^((q&7)<<4) ----
  char* pb = (char*)&ldsP[wave][0];
#pragma unroll
  for (int tm = 0; tm < 4; ++tm) {
#pragma unroll
    for (int tn = 0; tn < 4; ++tn) {
      unsigned lo = cvtpk(acc[tm][tn][0] * inv[tn], acc[tm][tn][1] * inv[tn]);
      unsigned hi = cvtpk(acc[tm][tn][2] * inv[tn], acc[tm][tn][3] * inv[tn]);
      int q = tn * 16 + l15;
      int off = (q * 128 + tm * 32 + rg * 8) ^ ((q & 7) << 4);
      *(unsigned long long*)(pb + off) = ((unsigned long long)hi << 32) | lo;
    }
  }

  // ---- PV: O = P*V (A = P from swizzled LDS, B = Vt rows, plain b128) ----
  floatx4 o[4][2] = {};
#pragma unroll
  for (int ks = 0; ks < 2; ++ks) {
    short8 af[4], vf[2];
#pragma unroll
    for (int qt = 0; qt < 4; ++qt) {
      int q = qt * 16 + l15;
      int off = (q * 128 + ks * 64 + rg * 16) ^ ((q & 7) << 4);
      af[qt] = *(const short8*)(pb + off);
    }
#pragma unroll
    for (int dt = 0; dt < 2; ++dt)
      vf[dt] = *(const short8*)&ldsVt[wave][(dt * 16 + l15) * 72 + ks * 32 + rg * 8];
#pragma unroll
    for (int qt = 0; qt < 4; ++qt)
#pragma unroll
      for (int dt = 0; dt < 2; ++dt)
        o[qt][dt] = __builtin_amdgcn_mfma_f32_16x16x32_bf16(
            af[qt], vf[dt], o[qt][dt], 0, 0, 0);
  }

  // ---- store O in place into Q columns (rows q<49) ----
#pragma unroll
  for (int qt = 0; qt < 4; ++qt) {
#pragma unroll
    for (int rr = 0; rr < 4; ++rr) {
      int q = qt * 16 + rg * 4 + rr;
      if (q < 49) {
#pragma unroll
        for (int dt = 0; dt < 2; ++dt)
          qkv[base + (size_t)q * 1536 + head * 32 + dt * 16 + l15] =
              f2bf(o[qt][dt][rr]);
      }
    }
  }
}

// -------------------------------------------------------------------------
extern "C" void kernel_launch(void* const* d_in, const int* in_sizes, int n_in,
                              void* d_out, int out_size, void* d_ws, size_t ws_size,
                              hipStream_t stream) {
  const float* x1     = (const float*)d_in[0];
  // d_in[1] = x2 : dead code in reference (xw[:,:,:C] uses only the x1 branch)
  const float* n1g    = (const float*)d_in[2];
  const float* n1b    = (const float*)d_in[3];
  const float* qkv_w  = (const float*)d_in[4];
  const float* qkv_b  = (const float*)d_in[5];
  const float* rel_t  = (const float*)d_in[6];
  const float* proj_w = (const float*)d_in[7];
  const float* proj_b = (const float*)d_in[8];
  const float* n2g    = (const float*)d_in[9];
  const float* n2b    = (const float*)d_in[10];
  const float* fc1_w  = (const float*)d_in[11];
  const float* fc1_b  = (const float*)d_in[12];
  const float* fc2_w  = (const float*)d_in[13];
  const float* fc2_b  = (const float*)d_in[14];
  float* outp = (float*)d_out;   // fp32; also holds x (residual-1 result)

  // ws layout (205,922,304 B), phase-aware:
  //  phase A: a1w [0..51,380,224) | bufQ [51,380,224..205,520,896)
  //  after QKV (a1w dead): pwbf | f1wbf | f2wbf | btab (1MB)
  //  after proj (bufQ dead): xln2 (overwrites btab) | hbuf
  //  qkv_wbf parks in d_out (dead until proj writes it).
  char* ws = (char*)d_ws;
  unsigned short* a1w    = (unsigned short*)ws;
  unsigned short* bufQ   = (unsigned short*)(ws + 51380224);
  unsigned short* pwbf   = (unsigned short*)ws;
  unsigned short* f1wbf  = (unsigned short*)(ws + 524288);
  unsigned short* f2wbf  = (unsigned short*)(ws + 2621440);
  float*          btabf  = (float*)(ws + 4718592);
  unsigned short* xln2   = (unsigned short*)(ws + 4718592);
  unsigned short* hbuf   = (unsigned short*)(ws + 56098816);
  unsigned short* qkvwbf = (unsigned short*)d_out;

  wcvt<<<384, 256, 0, stream>>>(qkv_w, qkvwbf, 98304);
  prep_ln1<<<TOKENS / 4, 256, 0, stream>>>(x1, n1g, n1b, a1w);
  gemm_glds<0><<<dim3(392, 12), 256, 0, stream>>>(
      a1w, qkvwbf, qkv_b, bufQ, nullptr, 1536, 512, 512);
  // a1w dead from here (stream-ordered): weight cvts + bias table build
  wcvt<<<128, 256, 0, stream>>>(proj_w, pwbf, 32768);
  wcvt<<<512, 256, 0, stream>>>(fc1_w, f1wbf, 131072);
  wcvt<<<512, 256, 0, stream>>>(fc2_w, f2wbf, 131072);
  btab_build<<<1024, 256, 0, stream>>>(rel_t, btabf);
  attn_mfma<<<4096, 256, 0, stream>>>(bufQ, btabf);
  gemm_glds<1><<<dim3(392, 4), 256, 0, stream>>>(
      bufQ, pwbf, proj_b, outp, x1, 512, 512, 1536);
  ln2_apply<<<TOKENS / 4, 256, 0, stream>>>(outp, n2g, n2b, xln2);
  for (int ch = 0; ch < 2; ++ch) {
    size_t ro = (size_t)ch * HTOK * 512;
    gemm_glds<2><<<dim3(196, 16), 256, 0, stream>>>(
        xln2 + ro, f1wbf, fc1_b, hbuf, nullptr, 2048, 512, 512);
    gemm_glds<3><<<dim3(196, 4), 256, 0, stream>>>(
        hbuf, f2wbf, fc2_b, outp + ro, outp + ro, 512, 2048, 2048);
  }
}

// Round 6
// 896.984 us; speedup vs baseline: 1.5309x; 1.0203x over previous
//
#include <hip/hip_runtime.h>
#include <math.h>

typedef __attribute__((ext_vector_type(8))) short short8;
typedef __attribute__((ext_vector_type(4))) float floatx4;

#define TOKENS 50176   // 16 * 64 windows * 49
#define HTOK   25088   // TOKENS/2 (fc1/fc2 row chunk)

__device__ __forceinline__ unsigned short f2bf(float f) {
  union { float f; unsigned int i; } x; x.f = f;
  unsigned int r = x.i + 0x7fffu + ((x.i >> 16) & 1u);
  return (unsigned short)(r >> 16);
}
__device__ __forceinline__ float bf2f(unsigned short u) {
  union { unsigned int i; float f; } x; x.i = ((unsigned int)u) << 16; return x.f;
}

// async global->LDS, 16B per lane; LDS dest = wave-uniform base + lane*16
__device__ __forceinline__ void gload16(const void* g, void* l) {
  __builtin_amdgcn_global_load_lds(
      (__attribute__((address_space(1))) void*)g,
      (__attribute__((address_space(3))) void*)l, 16, 0, 0);
}

__device__ __forceinline__ unsigned cvtpk(float lo, float hi) {
  unsigned r;
  asm("v_cvt_pk_bf16_f32 %0, %1, %2" : "=v"(r) : "v"(lo), "v"(hi));
  return r;
}

// -------------------------------------------------------------------------
// fp32 -> bf16 weight conversion (one-time). n8 = elements/8.
// -------------------------------------------------------------------------
__global__ __launch_bounds__(256) void wcvt(
    const float* __restrict__ src, unsigned short* __restrict__ dst, int n8) {
  int i = blockIdx.x * 256 + threadIdx.x;
  if (i >= n8) return;
  const float* p = src + (size_t)i * 8;
  floatx4 a = *(const floatx4*)p;
  floatx4 b = *(const floatx4*)(p + 4);
  short8 o;
#pragma unroll
  for (int k = 0; k < 4; ++k) { o[k] = (short)f2bf(a[k]); o[k + 4] = (short)f2bf(b[k]); }
  *(short8*)(dst + (size_t)i * 8) = o;
}

// -------------------------------------------------------------------------
// Combined rel-bias + shift-mask table: btab[cls][head][q(64)][k(64)] fp32.
// cls = (wh==7)*2 + (ww==7). k>=49 rows poisoned with -1e30 (valid-mask).
// -------------------------------------------------------------------------
__global__ __launch_bounds__(256) void btab_build(
    const float* __restrict__ relt, float* __restrict__ btab) {
  int idx = blockIdx.x * 256 + threadIdx.x;   // 4*16*64*64 = 262144
  int k = idx & 63;
  int q = (idx >> 6) & 63;
  int head = (idx >> 12) & 15;
  int cls = idx >> 16;
  float v;
  if (k >= 49) {
    v = -1e30f;
  } else if (q >= 49) {
    v = 0.f;
  } else {
    int iq = q / 7, jq = q % 7, ik = k / 7, jk = k % 7;
    int clsH = cls >> 1, clsW = cls & 1;
    int rq = (clsH ? ((iq < 4) ? 1 : 2) : 0) * 3 + (clsW ? ((jq < 4) ? 1 : 2) : 0);
    int rk = (clsH ? ((ik < 4) ? 1 : 2) : 0) * 3 + (clsW ? ((jk < 4) ? 1 : 2) : 0);
    int ridx = (iq - ik + 6) * 13 + (jq - jk + 6);
    v = relt[ridx * 16 + head] + ((rq != rk) ? -100.f : 0.f);
  }
  btab[idx] = v;
}

// -------------------------------------------------------------------------
// LN1 + roll(-3,-3) + window-partition gather, fp32 -> bf16.
// -------------------------------------------------------------------------
__global__ __launch_bounds__(256) void prep_ln1(
    const float* __restrict__ x1, const float* __restrict__ g,
    const float* __restrict__ b, unsigned short* __restrict__ a1w) {
  int gw = (blockIdx.x * 256 + threadIdx.x) >> 6;
  int lane = threadIdx.x & 63;
  if (gw >= TOKENS) return;
  int n = gw % 49, w = gw / 49;
  int i = n / 7, j = n % 7;
  int ww = w & 7, wh = (w >> 3) & 7, bb = w >> 6;
  int hs = (wh * 7 + i + 3) % 56;
  int wsS = (ww * 7 + j + 3) % 56;
  const float* rp = x1 + ((size_t)bb * 3136 + (size_t)hs * 56 + wsS) * 512 + lane * 8;
  floatx4 a0 = *(const floatx4*)rp;
  floatx4 a1 = *(const floatx4*)(rp + 4);
  float s = 0.f, ss = 0.f;
#pragma unroll
  for (int k = 0; k < 4; ++k) { s += a0[k]; ss += a0[k] * a0[k]; }
#pragma unroll
  for (int k = 0; k < 4; ++k) { s += a1[k]; ss += a1[k] * a1[k]; }
  for (int m = 32; m >= 1; m >>= 1) {
    s  += __shfl_xor(s, m, 64);
    ss += __shfl_xor(ss, m, 64);
  }
  float mu = s * (1.f / 512.f);
  float var = ss * (1.f / 512.f) - mu * mu;
  float rstd = rsqrtf(var + 1e-5f);
  floatx4 g0 = *(const floatx4*)(g + lane * 8);
  floatx4 g1 = *(const floatx4*)(g + lane * 8 + 4);
  floatx4 b0 = *(const floatx4*)(b + lane * 8);
  floatx4 b1 = *(const floatx4*)(b + lane * 8 + 4);
  short8 o8;
#pragma unroll
  for (int k = 0; k < 4; ++k) {
    o8[k]     = (short)f2bf((a0[k] - mu) * rstd * g0[k] + b0[k]);
    o8[k + 4] = (short)f2bf((a1[k] - mu) * rstd * g1[k] + b1[k]);
  }
  *(short8*)(a1w + (size_t)gw * 512 + lane * 8) = o8;
}

// -------------------------------------------------------------------------
// LN2 full apply: fp32 row -> normalized bf16 row. One wave per token.
// -------------------------------------------------------------------------
__global__ __launch_bounds__(256) void ln2_apply(
    const float* __restrict__ xin, const float* __restrict__ g,
    const float* __restrict__ b, unsigned short* __restrict__ outb) {
  int gw = (blockIdx.x * 256 + threadIdx.x) >> 6;
  int lane = threadIdx.x & 63;
  if (gw >= TOKENS) return;
  const float* rp = xin + (size_t)gw * 512 + lane * 8;
  floatx4 a0 = *(const floatx4*)rp;
  floatx4 a1 = *(const floatx4*)(rp + 4);
  float s = 0.f, ss = 0.f;
#pragma unroll
  for (int k = 0; k < 4; ++k) { s += a0[k]; ss += a0[k] * a0[k]; }
#pragma unroll
  for (int k = 0; k < 4; ++k) { s += a1[k]; ss += a1[k] * a1[k]; }
  for (int m = 32; m >= 1; m >>= 1) {
    s  += __shfl_xor(s, m, 64);
    ss += __shfl_xor(ss, m, 64);
  }
  float mu = s * (1.f / 512.f);
  float var = ss * (1.f / 512.f) - mu * mu;
  float rstd = rsqrtf(var + 1e-5f);
  floatx4 g0 = *(const floatx4*)(g + lane * 8);
  floatx4 g1 = *(const floatx4*)(g + lane * 8 + 4);
  floatx4 b0 = *(const floatx4*)(b + lane * 8);
  floatx4 b1 = *(const floatx4*)(b + lane * 8 + 4);
  short8 o8;
#pragma unroll
  for (int k = 0; k < 4; ++k) {
    o8[k]     = (short)f2bf((a0[k] - mu) * rstd * g0[k] + b0[k]);
    o8[k + 4] = (short)f2bf((a1[k] - mu) * rstd * g1[k] + b1[k]);
  }
  *(short8*)(outb + (size_t)gw * 512 + lane * 8) = o8;
}

// -------------------------------------------------------------------------
// m97-structure GEMM. Grid axes: blockIdx.x = COL tile (few), blockIdx.y =
// ROW tile (many) -> consecutive blocks share one A row-panel and sweep all
// col-tiles; B stays L2-resident, A streams from HBM once.
// EPI 0 folds attention SCALE into Q columns (n<512) — QKV only.
// -------------------------------------------------------------------------
template <int EPI>
__global__ __launch_bounds__(256, 2) void gemm_glds(
    const unsigned short* __restrict__ A,
    const unsigned short* __restrict__ Bw,
    const float* __restrict__ bias,
    void* __restrict__ outp,
    const float* __restrict__ res,
    int N, int K, int lda) {
  __shared__ unsigned short lA[128 * 64];
  __shared__ unsigned short lB[128 * 64];
  int tid = threadIdx.x;
  int wave = tid >> 6, lane = tid & 63;
  int rowt = blockIdx.y, colt = blockIdx.x;

  int srow = wave * 32 + (lane >> 3);
  int scol = (lane & 7) * 8;
  const unsigned short* gA[4];
  const unsigned short* gB[4];
#pragma unroll
  for (int i = 0; i < 4; ++i) {
    gA[i] = A + (size_t)(rowt * 128 + srow + i * 8) * lda + scol;
    gB[i] = Bw + (size_t)(colt * 128 + srow + i * 8) * K + scol;
  }
  unsigned short* lAp = &lA[wave * 2048];
  unsigned short* lBp = &lB[wave * 2048];

  int wm = (wave >> 1) * 64, wn = (wave & 1) * 64;
  int l15 = lane & 15, kq = (lane >> 4) * 8;
  int KT = K >> 6;
  floatx4 acc[4][4] = {};

  for (int kt = 0; kt < KT; ++kt) {
    int ko = kt * 64;
#pragma unroll
    for (int i = 0; i < 4; ++i) {
      gload16(gA[i] + ko, lAp + i * 512);
      gload16(gB[i] + ko, lBp + i * 512);
    }
    __syncthreads();
#pragma unroll
    for (int ks = 0; ks < 2; ++ks) {
      short8 af[4], bf8[4];
#pragma unroll
      for (int tm = 0; tm < 4; ++tm)
        af[tm] = *(const short8*)&lA[(wm + tm * 16 + l15) * 64 + ks * 32 + kq];
#pragma unroll
      for (int tn = 0; tn < 4; ++tn)
        bf8[tn] = *(const short8*)&lB[(wn + tn * 16 + l15) * 64 + ks * 32 + kq];
#pragma unroll
      for (int tm = 0; tm < 4; ++tm)
#pragma unroll
        for (int tn = 0; tn < 4; ++tn)
          acc[tm][tn] = __builtin_amdgcn_mfma_f32_16x16x32_bf16(
              af[tm], bf8[tn], acc[tm][tn], 0, 0, 0);
    }
    __syncthreads();
  }

  int colb = colt * 128 + wn + l15;
  int rowb = rowt * 128 + wm + ((lane >> 4) << 2);
#pragma unroll
  for (int tm = 0; tm < 4; ++tm) {
#pragma unroll
    for (int rg = 0; rg < 4; ++rg) {
      int m = rowb + tm * 16 + rg;
      size_t outrow;
      const float* resrow = nullptr;
      if (EPI == 1) {
        int nn = m % 49, wI = m / 49;
        int i = nn / 7, j = nn % 7;
        int wwI = wI & 7, whI = (wI >> 3) & 7, bb = wI >> 6;
        int hs = (whI * 7 + i + 3) % 56;
        int wsS = (wwI * 7 + j + 3) % 56;
        size_t orig = (size_t)bb * 3136 + (size_t)hs * 56 + wsS;
        outrow = orig * 512;
        resrow = res + orig * 512;
      } else {
        outrow = (size_t)m * N;
        if (EPI == 3) resrow = res + (size_t)m * 512;
      }
#pragma unroll
      for (int tn = 0; tn < 4; ++tn) {
        int n = colb + tn * 16;
        float v = acc[tm][tn][rg] + bias[n];
        if (EPI == 0 && n < 512) v *= 0.17677669529663687f;  // SCALE on Q cols
        if (EPI == 2) v = 0.5f * v * (1.f + erff(v * 0.70710678118654752f));
        if (EPI == 0 || EPI == 2) {
          ((unsigned short*)outp)[outrow + n] = f2bf(v);
        } else {
          ((float*)outp)[outrow + n] = v + resrow[n];
        }
      }
    }
  }
}

// -------------------------------------------------------------------------
// MFMA windowed attention (unchanged from round 5).
// -------------------------------------------------------------------------
__global__ __launch_bounds__(256, 3) void attn_mfma(
    unsigned short* qkv,                      // (1024*49, 1536) bf16, in/out
    const float* __restrict__ btab) {         // (4,16,64,64) fp32
  __shared__ unsigned short ldsVt[4][32 * 72];  // [wave][d][k] transposed V
  __shared__ unsigned short ldsP[4][4096];      // [wave][q*64 + k] swizzled
  int wave = threadIdx.x >> 6, lane = threadIdx.x & 63;
  int win = blockIdx.x >> 2, hg = blockIdx.x & 3;
  int head = hg * 4 + wave;
  int l15 = lane & 15, rg = lane >> 4;
  int wh = (win >> 3) & 7, ww = win & 7;
  int cls = (((wh == 7) ? 1 : 0) << 1) | ((ww == 7) ? 1 : 0);
  const size_t base = (size_t)win * 49 * 1536;
  const float* bt = btab + ((size_t)(cls * 16 + head) << 12);

  // ---- V reg-stage (global loads issued early; latency hides under QK) ----
  short8 vreg[4];
#pragma unroll
  for (int c = 0; c < 4; ++c) {
    int p = c >> 1, kh = c & 1;
    int k = kh * 32 + (lane >> 1);
    int kr = k < 49 ? k : 48;
    vreg[c] = *(const short8*)(qkv + base + (size_t)kr * 1536 + head * 32 +
                               1024 + p * 16 + (lane & 1) * 8);
  }

  // ---- QK^T (swapped): S^T tiles, frags direct from global ----
  short8 kf[4], qf[4];
#pragma unroll
  for (int t = 0; t < 4; ++t) {
    int r = t * 16 + l15; r = r < 49 ? r : 48;
    kf[t] = *(const short8*)(qkv + base + (size_t)r * 1536 + head * 32 + 512 + rg * 8);
    qf[t] = *(const short8*)(qkv + base + (size_t)r * 1536 + head * 32 + rg * 8);
  }
  floatx4 acc[4][4] = {};
#pragma unroll
  for (int tm = 0; tm < 4; ++tm)
#pragma unroll
    for (int tn = 0; tn < 4; ++tn)
      acc[tm][tn] = __builtin_amdgcn_mfma_f32_16x16x32_bf16(
          kf[tm], qf[tn], acc[tm][tn], 0, 0, 0);

  // ---- V -> LDS transposed: Vt[d][k], d-major, row stride 72 ----
  unsigned short* vt = &ldsVt[wave][0];
#pragma unroll
  for (int c = 0; c < 4; ++c) {
    int p = c >> 1, kh = c & 1;
    int k = kh * 32 + (lane >> 1);
    int d0 = p * 16 + (lane & 1) * 8;
#pragma unroll
    for (int j = 0; j < 8; ++j)
      vt[(d0 + j) * 72 + k] = (unsigned short)vreg[c][j];
  }

  // ---- + btab (bias+mask+valid fused), per-q-column max ----
  float mrow[4] = {-3e38f, -3e38f, -3e38f, -3e38f};
#pragma unroll
  for (int tn = 0; tn < 4; ++tn) {
    const float* btq = bt + (size_t)(tn * 16 + l15) * 64 + rg * 4;
#pragma unroll
    for (int tm = 0; tm < 4; ++tm) {
      floatx4 bv = *(const floatx4*)(btq + tm * 16);
#pragma unroll
      for (int rr = 0; rr < 4; ++rr) {
        float v = acc[tm][tn][rr] + bv[rr];
        acc[tm][tn][rr] = v;
        mrow[tn] = fmaxf(mrow[tn], v);
      }
    }
  }
#pragma unroll
  for (int tn = 0; tn < 4; ++tn) {
    mrow[tn] = fmaxf(mrow[tn], __shfl_xor(mrow[tn], 16, 64));
    mrow[tn] = fmaxf(mrow[tn], __shfl_xor(mrow[tn], 32, 64));
  }
  // ---- exp + sum ----
  float ssum[4] = {0.f, 0.f, 0.f, 0.f};
#pragma unroll
  for (int tm = 0; tm < 4; ++tm)
#pragma unroll
    for (int tn = 0; tn < 4; ++tn)
#pragma unroll
      for (int rr = 0; rr < 4; ++rr) {
        float e = __expf(acc[tm][tn][rr] - mrow[tn]);
        acc[tm][tn][rr] = e;
        ssum[tn] += e;
      }
#pragma unroll
  for (int tn = 0; tn < 4; ++tn) {
    ssum[tn] += __shfl_xor(ssum[tn], 16, 64);
    ssum[tn] += __shfl_xor(ssum[tn], 32, 64);
  }
  float inv[4];
#pragma unroll
  for (int tn = 0; tn < 4; ++tn) inv[tn] = 1.f / ssum[tn];

  // ---- P (normalized) -> LDS, A-layout [q][k] bf16, swizzle ^((q&7)<<4) ----
  char* pb = (char*)&ldsP[wave][0];
#pragma unroll
  for (int tm = 0; tm < 4; ++tm) {
#pragma unroll
    for (int tn = 0; tn < 4; ++tn) {
      unsigned lo = cvtpk(acc[tm][tn][0] * inv[tn], acc[tm][tn][1] * inv[tn]);
      unsigned hi = cvtpk(acc[tm][tn][2] * inv[tn], acc[tm][tn][3] * inv[tn]);
      int q = tn * 16 + l15;
      int off = (q * 128 + tm * 32 + rg * 8) ^ ((q & 7) << 4);
      *(unsigned long long*)(pb + off) = ((unsigned long long)hi << 32) | lo;
    }
  }

  // ---- PV: O = P*V (A = P from swizzled LDS, B = Vt rows, plain b128) ----
  floatx4 o[4][2] = {};
#pragma unroll
  for (int ks = 0; ks < 2; ++ks) {
    short8 af[4], vf[2];
#pragma unroll
    for (int qt = 0; qt < 4; ++qt) {
      int q = qt * 16 + l15;
      int off = (q * 128 + ks * 64 + rg * 16) ^ ((q & 7) << 4);
      af[qt] = *(const short8*)(pb + off);
    }
#pragma unroll
    for (int dt = 0; dt < 2; ++dt)
      vf[dt] = *(const short8*)&ldsVt[wave][(dt * 16 + l15) * 72 + ks * 32 + rg * 8];
#pragma unroll
    for (int qt = 0; qt < 4; ++qt)
#pragma unroll
      for (int dt = 0; dt < 2; ++dt)
        o[qt][dt] = __builtin_amdgcn_mfma_f32_16x16x32_bf16(
            af[qt], vf[dt], o[qt][dt], 0, 0, 0);
  }

  // ---- store O in place into Q columns (rows q<49) ----
#pragma unroll
  for (int qt = 0; qt < 4; ++qt) {
#pragma unroll
    for (int rr = 0; rr < 4; ++rr) {
      int q = qt * 16 + rg * 4 + rr;
      if (q < 49) {
#pragma unroll
        for (int dt = 0; dt < 2; ++dt)
          qkv[base + (size_t)q * 1536 + head * 32 + dt * 16 + l15] =
              f2bf(o[qt][dt][rr]);
      }
    }
  }
}

// -------------------------------------------------------------------------
extern "C" void kernel_launch(void* const* d_in, const int* in_sizes, int n_in,
                              void* d_out, int out_size, void* d_ws, size_t ws_size,
                              hipStream_t stream) {
  const float* x1     = (const float*)d_in[0];
  // d_in[1] = x2 : dead code in reference (xw[:,:,:C] uses only the x1 branch)
  const float* n1g    = (const float*)d_in[2];
  const float* n1b    = (const float*)d_in[3];
  const float* qkv_w  = (const float*)d_in[4];
  const float* qkv_b  = (const float*)d_in[5];
  const float* rel_t  = (const float*)d_in[6];
  const float* proj_w = (const float*)d_in[7];
  const float* proj_b = (const float*)d_in[8];
  const float* n2g    = (const float*)d_in[9];
  const float* n2b    = (const float*)d_in[10];
  const float* fc1_w  = (const float*)d_in[11];
  const float* fc1_b  = (const float*)d_in[12];
  const float* fc2_w  = (const float*)d_in[13];
  const float* fc2_b  = (const float*)d_in[14];
  float* outp = (float*)d_out;   // fp32; also holds x (residual-1 result)

  // ws layout (205,922,304 B), phase-aware:
  //  phase A: a1w [0..51,380,224) | bufQ [51,380,224..205,520,896)
  //  after QKV (a1w dead): pwbf | f1wbf | f2wbf | btab (1MB)
  //  after proj (bufQ dead): xln2 (overwrites btab) | hbuf
  //  qkv_wbf parks in d_out (dead until proj writes it).
  char* ws = (char*)d_ws;
  unsigned short* a1w    = (unsigned short*)ws;
  unsigned short* bufQ   = (unsigned short*)(ws + 51380224);
  unsigned short* pwbf   = (unsigned short*)ws;
  unsigned short* f1wbf  = (unsigned short*)(ws + 524288);
  unsigned short* f2wbf  = (unsigned short*)(ws + 2621440);
  float*          btabf  = (float*)(ws + 4718592);
  unsigned short* xln2   = (unsigned short*)(ws + 4718592);
  unsigned short* hbuf   = (unsigned short*)(ws + 56098816);
  unsigned short* qkvwbf = (unsigned short*)d_out;

  wcvt<<<384, 256, 0, stream>>>(qkv_w, qkvwbf, 98304);
  prep_ln1<<<TOKENS / 4, 256, 0, stream>>>(x1, n1g, n1b, a1w);
  gemm_glds<0><<<dim3(12, 392), 256, 0, stream>>>(
      a1w, qkvwbf, qkv_b, bufQ, nullptr, 1536, 512, 512);
  // a1w dead from here (stream-ordered): weight cvts + bias table build
  wcvt<<<128, 256, 0, stream>>>(proj_w, pwbf, 32768);
  wcvt<<<512, 256, 0, stream>>>(fc1_w, f1wbf, 131072);
  wcvt<<<512, 256, 0, stream>>>(fc2_w, f2wbf, 131072);
  btab_build<<<1024, 256, 0, stream>>>(rel_t, btabf);
  attn_mfma<<<4096, 256, 0, stream>>>(bufQ, btabf);
  gemm_glds<1><<<dim3(4, 392), 256, 0, stream>>>(
      bufQ, pwbf, proj_b, outp, x1, 512, 512, 1536);
  ln2_apply<<<TOKENS / 4, 256, 0, stream>>>(outp, n2g, n2b, xln2);
  for (int ch = 0; ch < 2; ++ch) {
    size_t ro = (size_t)ch * HTOK * 512;
    gemm_glds<2><<<dim3(16, 196), 256, 0, stream>>>(
        xln2 + ro, f1wbf, fc1_b, hbuf, nullptr, 2048, 512, 512);
    gemm_glds<3><<<dim3(4, 196), 256, 0, stream>>>(
        hbuf, f2wbf, fc2_b, outp + ro, outp + ro, 512, 2048, 2048);
  }
}